// Round 3
// baseline (393.141 us; speedup 1.0000x reference)
//
#include <hip/hip_runtime.h>
#include <math.h>

// Problem constants (from setup_inputs: B=128, N=512, C=64)
#define BB 128
#define NN 512
#define CC 64
#define FS 16
#define RES 497          // N - FS + 1
#define MAXP 256         // ceil(N * 0.5)
#define BN (BB*NN)       // 65536
#define GT (BB*RES*FS)   // 1017856 gumbel elements

// ---------------- Threefry-2x32 (JAX key (0,777)) ----------------
__device__ __forceinline__ unsigned rotl32(unsigned x, int d){ return (x<<d)|(x>>(32-d)); }

__device__ __forceinline__ void threefry777(unsigned x0, unsigned x1, unsigned &o0, unsigned &o1){
  const unsigned ks0 = 0u, ks1 = 777u;
  const unsigned ks2 = 0x1BD11BDAu ^ ks0 ^ ks1;
  x0 += ks0; x1 += ks1;
  x0+=x1; x1=rotl32(x1,13); x1^=x0;
  x0+=x1; x1=rotl32(x1,15); x1^=x0;
  x0+=x1; x1=rotl32(x1,26); x1^=x0;
  x0+=x1; x1=rotl32(x1, 6); x1^=x0;
  x0+=ks1; x1+=ks2+1u;
  x0+=x1; x1=rotl32(x1,17); x1^=x0;
  x0+=x1; x1=rotl32(x1,29); x1^=x0;
  x0+=x1; x1=rotl32(x1,16); x1^=x0;
  x0+=x1; x1=rotl32(x1,24); x1^=x0;
  x0+=ks2; x1+=ks0+2u;
  x0+=x1; x1=rotl32(x1,13); x1^=x0;
  x0+=x1; x1=rotl32(x1,15); x1^=x0;
  x0+=x1; x1=rotl32(x1,26); x1^=x0;
  x0+=x1; x1=rotl32(x1, 6); x1^=x0;
  x0+=ks0; x1+=ks1+3u;
  x0+=x1; x1=rotl32(x1,17); x1^=x0;
  x0+=x1; x1=rotl32(x1,29); x1^=x0;
  x0+=x1; x1=rotl32(x1,16); x1^=x0;
  x0+=x1; x1=rotl32(x1,24); x1^=x0;
  x0+=ks1; x1+=ks2+4u;
  x0+=x1; x1=rotl32(x1,13); x1^=x0;
  x0+=x1; x1=rotl32(x1,15); x1^=x0;
  x0+=x1; x1=rotl32(x1,26); x1^=x0;
  x0+=x1; x1=rotl32(x1, 6); x1^=x0;
  x0+=ks2; x1+=ks0+5u;
  o0 = x0; o1 = x1;
}

// Gumbel element p of the flat (B,RES,FS) array.
// JAX threefry_partitionable=True (modern default): per-element 64-bit counter
// (hi=0, lo=p) hashed once; 32-bit draw = o0 ^ o1. Uniform->gumbel kept in f32
// (reference dtype is explicit jnp.float32), promoted to f64 at the use site.
__device__ __forceinline__ float gumbel_at_f32(unsigned p){
  unsigned o0, o1;
  threefry777(0u, p, o0, o1);
  unsigned bits = o0 ^ o1;
  float fl = __uint_as_float((bits >> 9) | 0x3f800000u) - 1.0f;  // [0,1) f32
  float u  = fmaxf(1.17549435e-38f, fl);                          // minval = tiny
  float inner = -logf(u);     // f32, ocml
  return -logf(inner);        // f32, ocml
}

// ---------------- K1: f64 scores + a1/a2 dots per node ----------------
__global__ void k_scores(const float* __restrict__ x, const float* __restrict__ w,
                         const float* __restrict__ bsc, const float* __restrict__ att,
                         double* __restrict__ scoresd, double* __restrict__ s1d,
                         double* __restrict__ s2d){
  int n = blockIdx.x*blockDim.x + threadIdx.x;
  if (n >= BN) return;
  double wn = 0.0;
  #pragma unroll
  for (int c=0;c<CC;c++){ double wv = (double)w[c]; wn += wv*wv; }
  const float* xr = x + (size_t)n*CC;
  double dw=0.0, d1=0.0, d2=0.0;
  #pragma unroll
  for (int c=0;c<CC;c++){
    double xv = (double)xr[c];
    dw += xv * (double)w[c];
    d1 += xv * (double)att[c];
    d2 += xv * (double)att[CC + c];
  }
  scoresd[n] = (dw + (double)bsc[0]) / sqrt(wn);
  s1d[n] = d1;
  s2d[n] = d2;
}

// ---------------- K2: stable descending argsort per graph (bitonic, f64 keys) ----------------
__global__ void k_sort(const double* __restrict__ scoresd, int* __restrict__ perm){
  int b = blockIdx.x;
  __shared__ double ss[NN];
  __shared__ int    si[NN];
  int t = threadIdx.x;
  ss[t] = scoresd[b*NN + t];
  si[t] = t;
  __syncthreads();
  for (int k = 2; k <= NN; k <<= 1){
    for (int j = k >> 1; j > 0; j >>= 1){
      int ixj = t ^ j;
      if (ixj > t){
        double s0 = ss[t], s1v = ss[ixj];
        int    i0 = si[t], i1  = si[ixj];
        // "before" = (score desc, idx asc) — total order (indices unique)
        bool before = (s0 > s1v) || (s0 == s1v && i0 < i1);
        bool up = ((t & k) == 0);
        if (up ? !before : before){
          ss[t] = s1v; ss[ixj] = s0;
          si[t] = i1;  si[ixj] = i0;
        }
      }
      __syncthreads();
    }
  }
  perm[b*NN + t] = si[t];
}

// ---------------- K3: per-graph block: gk rows, sm softmax, stable desc sort of gk,
//                    and deterministic column-sum of sorted sm (all f64) ----------------
__global__ void k_passA(const float* __restrict__ x, const int* __restrict__ perm,
                        const double* __restrict__ s1d, const double* __restrict__ s2d,
                        double* __restrict__ gkd, unsigned char* __restrict__ ord8,
                        double* __restrict__ colsumd){
  int b = blockIdx.x;
  int tid = threadIdx.x;
  __shared__ double s1g[NN], s2g[NN];   // 8 KB
  __shared__ int    pg[NN];             // 2 KB
  __shared__ double wred[4][FS];        // 512 B
  for (int i = tid; i < NN; i += 256){
    int p = perm[b*NN + i];
    pg[i]  = p;
    s1g[i] = s1d[b*NN + p];
    s2g[i] = s2d[b*NN + p];
  }
  __syncthreads();

  double acc[FS];
  #pragma unroll
  for (int s=0;s<FS;s++) acc[s] = 0.0;

  for (int i = tid; i < RES; i += 256){
    const float* xrow[FS];
    #pragma unroll
    for (int j=0;j<FS;j++) xrow[j] = x + (size_t)(b*NN + pg[i+j])*CC;
    const float* xs = xrow[0];  // src row == dst row j=0

    double sq[FS];
    #pragma unroll
    for (int j=0;j<FS;j++) sq[j] = 0.0;
    for (int c=0;c<CC;c++){
      double sv = (double)xs[c];
      #pragma unroll
      for (int j=0;j<FS;j++){
        double df = sv - (double)xrow[j][c];
        sq[j] += df*df;
      }
    }
    double gkv[FS];
    #pragma unroll
    for (int j=0;j<FS;j++){
      double d = (sq[j] > 0.0) ? sqrt(sq[j]) : 0.0;   // safe_norm
      gkv[j] = exp(-d/2.0) - 1e-20;
    }

    // softmax over window (f64, max-subtracted like jax.nn.softmax)
    double smt[FS];
    double s1v = s1g[i];
    #pragma unroll
    for (int j=0;j<FS;j++) smt[j] = s1v + s2g[i+j];
    double m = smt[0];
    #pragma unroll
    for (int j=1;j<FS;j++) m = fmax(m, smt[j]);
    double em[FS]; double ssum = 0.0;
    #pragma unroll
    for (int j=0;j<FS;j++){ em[j] = exp(smt[j]-m); ssum += em[j]; }

    // stable descending selection-sort by gk (strict > keeps earliest index)
    size_t base = ((size_t)b*RES + i)*FS;
    unsigned used = 0u;
    for (int s=0;s<FS;s++){
      double bv = 0.0; int bj = -1;
      #pragma unroll
      for (int j=0;j<FS;j++){
        bool free_j = (((used>>j)&1u)==0u);
        if (free_j && (bj < 0 || gkv[j] > bv)){ bv = gkv[j]; bj = j; }
      }
      used |= (1u<<bj);
      ord8[base+s] = (unsigned char)bj;
      acc[s] += em[bj]/ssum;           // sorted sm, same values as ref's gather
    }
    #pragma unroll
    for (int j=0;j<FS;j++) gkd[base+j] = gkv[j];
  }

  // deterministic reduction: wave shuffle tree, then fixed-order cross-wave sum
  int lane = tid & 63, wid = tid >> 6;
  #pragma unroll
  for (int s=0;s<FS;s++){
    double v = acc[s];
    for (int off=32; off>0; off>>=1) v += __shfl_down(v, off, 64);
    if (lane == 0) wred[wid][s] = v;
  }
  __syncthreads();
  if (tid < FS){
    colsumd[b*FS + tid] = wred[0][tid] + wred[1][tid] + wred[2][tid] + wred[3][tid];
  }
}

// ---------------- K4: gumbel-softmax, ths, shifted (out), delta (f64; gumbel f32) ----------------
__global__ void k_gumbel(const double* __restrict__ gkd, const unsigned char* __restrict__ ord8,
                         const double* __restrict__ colsumd, const int* __restrict__ epoch_p,
                         float* __restrict__ shifted_out, int* __restrict__ delta){
  int t = blockIdx.x*blockDim.x + threadIdx.x;
  if (t >= BB*RES) return;
  int b = t / RES;
  size_t base = (size_t)t * FS;
  double tau = 10.0 * pow(0.01, (double)epoch_p[0] / 100.0);

  double z[FS];
  #pragma unroll
  for (int s=0;s<FS;s++){
    if (s == 0){ z[s] = -INFINITY; continue; }
    double g = (double)gumbel_at_f32((unsigned)(base + (size_t)s));
    z[s] = (g + colsumd[b*FS + s]) / tau;
  }
  double m = z[1];
  #pragma unroll
  for (int s=2;s<FS;s++) m = fmax(m, z[s]);
  double e[FS]; double ssum = 0.0;
  e[0] = 0.0;
  #pragma unroll
  for (int s=1;s<FS;s++){ e[s] = exp(z[s]-m); ssum += e[s]; }

  double ths = 0.0;
  #pragma unroll
  for (int s=0;s<FS;s++){
    ths += gkd[base + (size_t)ord8[base+s]] * (e[s]/ssum);
  }

  double shv[FS];
  #pragma unroll
  for (int j=0;j<FS;j++){
    shv[j] = fmax(gkd[base+j] - ths, 0.0);
    shifted_out[base+j] = (float)shv[j];
  }
  double bv = shv[1]; int bj = 1;
  #pragma unroll
  for (int j=2;j<FS;j++){ if (shv[j] < bv){ bv = shv[j]; bj = j; } }
  delta[t] = bj;   // argmin over [1:] plus 1 == the j index itself
}

// ---------------- K5: serial pivot chain per graph ----------------
__global__ void k_chain(const int* __restrict__ delta, float* __restrict__ piv_out,
                        int* __restrict__ pivi){
  int b = blockIdx.x*blockDim.x + threadIdx.x;
  if (b >= BB) return;
  const int* db = delta + b*RES;
  int ptr = 0;
  for (int p=0;p<MAXP;p++){
    int piv;
    if (ptr < RES){ piv = ptr; ptr = ptr + db[ptr]; }
    else          { piv = -1;  ptr = RES; }
    piv_out[b*MAXP + p] = (float)piv;   // harness reads d_out as f32
    pivi[b*MAXP + p]    = piv;
  }
}

// ---------------- K6: pooled gather (masked) ----------------
__global__ void k_pool(const float* __restrict__ x, const int* __restrict__ perm,
                       const int* __restrict__ pivi, float* __restrict__ pooled){
  int t = blockIdx.x*blockDim.x + threadIdx.x;   // (b*MAXP+p)*(C/4) + c4
  const int total = BB*MAXP*(CC/4);
  if (t >= total) return;
  int c4 = t & 15;
  int bp = t >> 4;
  int piv = pivi[bp];
  float4 v = make_float4(0.f,0.f,0.f,0.f);
  if (piv >= 0){
    int b = bp / MAXP;
    int src = perm[b*NN + piv];
    const float4* xr = (const float4*)(x + (size_t)(b*NN + src)*CC);
    v = xr[c4];
  }
  ((float4*)pooled)[t] = v;
}

extern "C" void kernel_launch(void* const* d_in, const int* in_sizes, int n_in,
                              void* d_out, int out_size, void* d_ws, size_t ws_size,
                              hipStream_t stream) {
  (void)in_sizes; (void)n_in; (void)out_size; (void)ws_size;
  const float* x    = (const float*)d_in[0];
  const float* w    = (const float*)d_in[1];
  const float* bsc  = (const float*)d_in[2];
  const float* att  = (const float*)d_in[3];
  const int*   epch = (const int*)d_in[5];

  // workspace layout (doubles first for alignment), total ≈ 11.4 MB
  double* scoresd = (double*)d_ws;
  double* s1d     = scoresd + BN;
  double* s2d     = s1d + BN;
  double* colsumd = s2d + BN;
  double* gkd     = colsumd + BB*FS;
  int*    perm    = (int*)(gkd + GT);
  int*    delta   = perm + BN;
  int*    pivi    = delta + BB*RES;
  unsigned char* ord8 = (unsigned char*)(pivi + BB*MAXP);

  float* out_pooled  = (float*)d_out;                   // B*MAXP*C
  float* out_shifted = out_pooled + BB*MAXP*CC;         // B*RES*FS
  float* out_piv     = out_shifted + (size_t)BB*RES*FS; // B*MAXP (as float)

  k_scores<<<(BN+255)/256, 256, 0, stream>>>(x, w, bsc, att, scoresd, s1d, s2d);
  k_sort  <<<BB, NN, 0, stream>>>(scoresd, perm);
  k_passA <<<BB, 256, 0, stream>>>(x, perm, s1d, s2d, gkd, ord8, colsumd);
  k_gumbel<<<(BB*RES+255)/256, 256, 0, stream>>>(gkd, ord8, colsumd, epch, out_shifted, delta);
  k_chain <<<1, BB, 0, stream>>>(delta, out_piv, pivi);
  k_pool  <<<(BB*MAXP*(CC/4)+255)/256, 256, 0, stream>>>(x, perm, pivi, out_pooled);
}

// Round 4
// 84.870 us; speedup vs baseline: 4.6323x; 4.6323x over previous
//
#include <hip/hip_runtime.h>
#include <math.h>

// Problem constants (from setup_inputs: B=128, N=512, C=64)
#define BB 128
#define NN 512
#define CC 64
#define FS 16
#define RES 497          // N - FS + 1
#define MAXP 256         // ceil(N * 0.5)
#define BN (BB*NN)       // 65536
#define GT (BB*RES*FS)   // 1017856
#define NCH 4            // window chunks per graph
#define CHW 128          // windows per chunk (last chunk: 113)
#define MAXR (CHW+FS-1)  // 143 rows staged per chunk
#define PITCH 65         // LDS row pitch (floats) -> conflict-free strided reads

// ---------------- Threefry-2x32 (JAX key (0,777), partitionable) ----------------
__device__ __forceinline__ unsigned rotl32(unsigned x, int d){ return (x<<d)|(x>>(32-d)); }

__device__ __forceinline__ void threefry777(unsigned x0, unsigned x1, unsigned &o0, unsigned &o1){
  const unsigned ks0 = 0u, ks1 = 777u;
  const unsigned ks2 = 0x1BD11BDAu ^ ks0 ^ ks1;
  x0 += ks0; x1 += ks1;
  x0+=x1; x1=rotl32(x1,13); x1^=x0;
  x0+=x1; x1=rotl32(x1,15); x1^=x0;
  x0+=x1; x1=rotl32(x1,26); x1^=x0;
  x0+=x1; x1=rotl32(x1, 6); x1^=x0;
  x0+=ks1; x1+=ks2+1u;
  x0+=x1; x1=rotl32(x1,17); x1^=x0;
  x0+=x1; x1=rotl32(x1,29); x1^=x0;
  x0+=x1; x1=rotl32(x1,16); x1^=x0;
  x0+=x1; x1=rotl32(x1,24); x1^=x0;
  x0+=ks2; x1+=ks0+2u;
  x0+=x1; x1=rotl32(x1,13); x1^=x0;
  x0+=x1; x1=rotl32(x1,15); x1^=x0;
  x0+=x1; x1=rotl32(x1,26); x1^=x0;
  x0+=x1; x1=rotl32(x1, 6); x1^=x0;
  x0+=ks0; x1+=ks1+3u;
  x0+=x1; x1=rotl32(x1,17); x1^=x0;
  x0+=x1; x1=rotl32(x1,29); x1^=x0;
  x0+=x1; x1=rotl32(x1,16); x1^=x0;
  x0+=x1; x1=rotl32(x1,24); x1^=x0;
  x0+=ks1; x1+=ks2+4u;
  x0+=x1; x1=rotl32(x1,13); x1^=x0;
  x0+=x1; x1=rotl32(x1,15); x1^=x0;
  x0+=x1; x1=rotl32(x1,26); x1^=x0;
  x0+=x1; x1=rotl32(x1, 6); x1^=x0;
  x0+=ks2; x1+=ks0+5u;
  o0 = x0; o1 = x1;
}

// Gumbel element p of flat (B,RES,FS): partitionable counter (0,p), bits=o0^o1,
// f32 uniform->gumbel (reference dtype), promoted to f64 at use site.
__device__ __forceinline__ float gumbel_at_f32(unsigned p){
  unsigned o0, o1;
  threefry777(0u, p, o0, o1);
  unsigned bits = o0 ^ o1;
  float fl = __uint_as_float((bits >> 9) | 0x3f800000u) - 1.0f;  // [0,1)
  float u  = fmaxf(1.17549435e-38f, fl);
  return -logf(-logf(u));
}

// ---------------- K1: f64 scores + a1/a2 dots per node ----------------
__global__ void k_scores(const float* __restrict__ x, const float* __restrict__ w,
                         const float* __restrict__ bsc, const float* __restrict__ att,
                         double* __restrict__ scoresd, double* __restrict__ s1d,
                         double* __restrict__ s2d){
  int n = blockIdx.x*blockDim.x + threadIdx.x;
  if (n >= BN) return;
  double wn = 0.0;
  #pragma unroll
  for (int c=0;c<CC;c++){ double wv = (double)w[c]; wn += wv*wv; }
  const float* xr = x + (size_t)n*CC;
  double dw=0.0, d1=0.0, d2=0.0;
  #pragma unroll
  for (int c=0;c<CC;c++){
    double xv = (double)xr[c];
    dw += xv * (double)w[c];
    d1 += xv * (double)att[c];
    d2 += xv * (double)att[CC + c];
  }
  scoresd[n] = (dw + (double)bsc[0]) / sqrt(wn);
  s1d[n] = d1;
  s2d[n] = d2;
}

// ---------------- K2: stable descending argsort per graph (bitonic, f64 keys) ----------------
__global__ void k_sort(const double* __restrict__ scoresd, int* __restrict__ perm){
  int b = blockIdx.x;
  __shared__ double ss[NN];
  __shared__ int    si[NN];
  int t = threadIdx.x;
  ss[t] = scoresd[b*NN + t];
  si[t] = t;
  __syncthreads();
  for (int k = 2; k <= NN; k <<= 1){
    for (int j = k >> 1; j > 0; j >>= 1){
      int ixj = t ^ j;
      if (ixj > t){
        double s0 = ss[t], s1v = ss[ixj];
        int    i0 = si[t], i1  = si[ixj];
        bool before = (s0 > s1v) || (s0 == s1v && i0 < i1);
        bool up = ((t & k) == 0);
        if (up ? !before : before){
          ss[t] = s1v; ss[ixj] = s0;
          si[t] = i1;  si[ixj] = i0;
        }
      }
      __syncthreads();
    }
  }
  perm[b*NN + t] = si[t];
}

// Batcher odd-even mergesort network, n=16 (63 comparators), fully static indices.
// Sorts ascending in "before" order: (gk desc, idx asc). Stable-equivalent (total order).
#define CE(A,B) { bool sw = !((gkv[A] > gkv[B]) || (gkv[A]==gkv[B] && sidx[A] < sidx[B])); \
  if (sw){ double t0=gkv[A]; gkv[A]=gkv[B]; gkv[B]=t0; \
           double t1=em[A];  em[A]=em[B];  em[B]=t1;  \
           int    t2=sidx[A];sidx[A]=sidx[B];sidx[B]=t2; } }

// ---------------- K3: per (graph, chunk): LDS-staged windows -> gk, ord, colsum partial ----------------
__global__ __launch_bounds__(CHW) void k_passA(const float* __restrict__ x,
                        const int* __restrict__ perm,
                        const double* __restrict__ s1d, const double* __restrict__ s2d,
                        double* __restrict__ gkd, unsigned char* __restrict__ ord8,
                        double* __restrict__ partial){
  int b = blockIdx.y, ch = blockIdx.x, tid = threadIdx.x;
  int i0 = ch*CHW;
  int nwin  = min(CHW, RES - i0);
  int nrows = min(NN - i0, nwin + FS - 1);
  __shared__ float  xs[MAXR*PITCH];     // 37.2 KB
  __shared__ double s1g[MAXR], s2g[MAXR];
  __shared__ int    pg[MAXR];
  __shared__ double wred[2][FS];

  for (int r = tid; r < nrows; r += CHW) pg[r] = perm[b*NN + i0 + r];
  __syncthreads();
  // coalesced row staging: 16 threads/row (float4), 8 rows per pass
  for (int r0 = 0; r0 < nrows; r0 += CHW/16){
    int r = r0 + (tid >> 4);
    if (r < nrows){
      int seg = tid & 15;
      float4 v = ((const float4*)(x + (size_t)(b*NN + pg[r])*CC))[seg];
      int o = r*PITCH + seg*4;
      xs[o]=v.x; xs[o+1]=v.y; xs[o+2]=v.z; xs[o+3]=v.w;
    }
  }
  for (int r = tid; r < nrows; r += CHW){
    s1g[r] = s1d[b*NN + pg[r]];
    s2g[r] = s2d[b*NN + pg[r]];
  }
  __syncthreads();

  bool act = (tid < nwin);
  size_t base = ((size_t)b*RES + i0 + tid)*FS;

  double gkv[FS], em[FS]; int sidx[FS];
  double ssum = 1.0;
  {
    double sq[FS];
    #pragma unroll
    for (int j=0;j<FS;j++) sq[j] = 0.0;
    for (int c=0;c<CC;c++){
      double sv = (double)xs[tid*PITCH + c];
      #pragma unroll
      for (int j=0;j<FS;j++){
        double df = sv - (double)xs[(tid+j)*PITCH + c];
        sq[j] += df*df;
      }
    }
    #pragma unroll
    for (int j=0;j<FS;j++){
      double d = (sq[j] > 0.0) ? sqrt(sq[j]) : 0.0;   // safe_norm
      gkv[j] = exp(-d/2.0) - 1e-20;
    }
  }
  if (act){
    #pragma unroll
    for (int j=0;j<FS;j++) gkd[base+j] = gkv[j];      // unsorted gk (before in-place sort)
  }
  {
    // window softmax (f64, max-subtracted)
    double smt[FS];
    double s1v = s1g[tid];
    #pragma unroll
    for (int j=0;j<FS;j++) smt[j] = s1v + s2g[tid + j];
    double m = smt[0];
    #pragma unroll
    for (int j=1;j<FS;j++) m = fmax(m, smt[j]);
    ssum = 0.0;
    #pragma unroll
    for (int j=0;j<FS;j++){ em[j] = exp(smt[j]-m); ssum += em[j]; }
  }
  #pragma unroll
  for (int j=0;j<FS;j++) sidx[j] = j;

  // static Batcher network: sort (gkv, em, sidx) by (gk desc, idx asc)
  CE(0,1) CE(2,3) CE(4,5) CE(6,7) CE(8,9) CE(10,11) CE(12,13) CE(14,15)
  CE(0,2) CE(1,3) CE(4,6) CE(5,7) CE(8,10) CE(9,11) CE(12,14) CE(13,15)
  CE(1,2) CE(5,6) CE(9,10) CE(13,14)
  CE(0,4) CE(1,5) CE(2,6) CE(3,7) CE(8,12) CE(9,13) CE(10,14) CE(11,15)
  CE(2,4) CE(3,5) CE(10,12) CE(11,13)
  CE(1,2) CE(3,4) CE(5,6) CE(9,10) CE(11,12) CE(13,14)
  CE(0,8) CE(1,9) CE(2,10) CE(3,11) CE(4,12) CE(5,13) CE(6,14) CE(7,15)
  CE(4,8) CE(5,9) CE(6,10) CE(7,11)
  CE(2,4) CE(3,5) CE(6,8) CE(7,9) CE(10,12) CE(11,13)
  CE(1,2) CE(3,4) CE(5,6) CE(7,8) CE(9,10) CE(11,12) CE(13,14)

  if (act){
    #pragma unroll
    for (int s=0;s<FS;s++) ord8[base+s] = (unsigned char)sidx[s];
  }

  // deterministic colsum partial: wave butterfly-free shfl_down tree + 2-wave combine
  int lane = tid & 63, wv = tid >> 6;
  #pragma unroll
  for (int s=0;s<FS;s++){
    double v = act ? (em[s]/ssum) : 0.0;
    #pragma unroll
    for (int off=32; off; off>>=1) v += __shfl_down(v, off, 64);
    if (lane == 0) wred[wv][s] = v;
  }
  __syncthreads();
  if (tid < FS) partial[((size_t)b*NCH + ch)*FS + tid] = wred[0][tid] + wred[1][tid];
}

// ---------------- K4: 16 lanes per window: gumbel-softmax, ths, shifted, delta ----------------
__global__ void k_gumbel(const double* __restrict__ gkd, const unsigned char* __restrict__ ord8,
                         const double* __restrict__ partial, const int* __restrict__ epoch_p,
                         float* __restrict__ shifted_out, int* __restrict__ delta){
  int t = blockIdx.x*blockDim.x + threadIdx.x;
  int win = t >> 4, s = t & 15;
  if (win >= BB*RES) return;
  int b = win / RES;
  size_t base = (size_t)win * FS;
  double tau = 10.0 * pow(0.01, (double)epoch_p[0] / 100.0);

  double cs = 0.0;
  #pragma unroll
  for (int k=0;k<NCH;k++) cs += partial[((size_t)b*NCH + k)*FS + s];

  double z;
  if (s == 0) z = -(double)INFINITY;
  else {
    double g = (double)gumbel_at_f32((unsigned)(base + (unsigned)s));
    z = (g + cs) / tau;
  }
  double m = z;
  #pragma unroll
  for (int off=8; off; off>>=1) m = fmax(m, __shfl_xor(m, off, 16));
  double e = (s == 0) ? 0.0 : exp(z - m);
  double ssum = e;
  #pragma unroll
  for (int off=8; off; off>>=1) ssum += __shfl_xor(ssum, off, 16);

  double gks = gkd[base + (size_t)ord8[base + s]];
  double ths = gks * (e/ssum);
  #pragma unroll
  for (int off=8; off; off>>=1) ths += __shfl_xor(ths, off, 16);

  double shv = fmax(gkd[base + s] - ths, 0.0);
  shifted_out[base + s] = (float)shv;

  double av = (s == 0) ? (double)INFINITY : shv;   // argmin over j=1..15, first-min wins
  int ai = s;
  #pragma unroll
  for (int off=8; off; off>>=1){
    double ov = __shfl_xor(av, off, 16);
    int    oi = __shfl_xor(ai, off, 16);
    if (ov < av || (ov == av && oi < ai)){ av = ov; ai = oi; }
  }
  if (s == 0) delta[win] = ai;
}

// ---------------- K5: pivot chain via pointer-doubling jump tables ----------------
__global__ __launch_bounds__(256) void k_chain(const int* __restrict__ delta,
                                               float* __restrict__ piv_out,
                                               int* __restrict__ pivi){
  int b = blockIdx.x, tid = threadIdx.x;
  __shared__ int tbl[8][512];
  for (int i = tid; i < 512; i += 256){
    int v;
    if (i < RES){ v = i + delta[b*RES + i]; if (v > RES) v = RES; }
    else v = RES;                 // absorbing sentinel
    tbl[0][i] = v;
  }
  __syncthreads();
  #pragma unroll
  for (int k=1;k<8;k++){
    int v0 = tbl[k-1][tid];
    int v1 = tbl[k-1][tid+256];
    tbl[k][tid]     = tbl[k-1][v0];
    tbl[k][tid+256] = tbl[k-1][v1];
    __syncthreads();
  }
  int p = 0;
  #pragma unroll
  for (int k=0;k<8;k++) if ((tid>>k)&1) p = tbl[k][p];
  int piv = (p < RES) ? p : -1;
  piv_out[b*MAXP + tid] = (float)piv;
  pivi[b*MAXP + tid]    = piv;
}

// ---------------- K6: pooled gather (masked) ----------------
__global__ void k_pool(const float* __restrict__ x, const int* __restrict__ perm,
                       const int* __restrict__ pivi, float* __restrict__ pooled){
  int t = blockIdx.x*blockDim.x + threadIdx.x;
  const int total = BB*MAXP*(CC/4);
  if (t >= total) return;
  int c4 = t & 15;
  int bp = t >> 4;
  int piv = pivi[bp];
  float4 v = make_float4(0.f,0.f,0.f,0.f);
  if (piv >= 0){
    int b = bp / MAXP;
    int src = perm[b*NN + piv];
    v = ((const float4*)(x + (size_t)(b*NN + src)*CC))[c4];
  }
  ((float4*)pooled)[t] = v;
}

extern "C" void kernel_launch(void* const* d_in, const int* in_sizes, int n_in,
                              void* d_out, int out_size, void* d_ws, size_t ws_size,
                              hipStream_t stream) {
  (void)in_sizes; (void)n_in; (void)out_size; (void)ws_size;
  const float* x    = (const float*)d_in[0];
  const float* w    = (const float*)d_in[1];
  const float* bsc  = (const float*)d_in[2];
  const float* att  = (const float*)d_in[3];
  const int*   epch = (const int*)d_in[5];

  // workspace layout (~10.9 MiB; scoresd reused as colsum partials after k_sort)
  double* scoresd = (double*)d_ws;
  double* partial = scoresd;                 // BB*NCH*FS doubles, alias (scores dead post-sort)
  double* s1d     = scoresd + BN;
  double* s2d     = s1d + BN;
  double* gkd     = s2d + BN;
  int*    perm    = (int*)(gkd + GT);
  int*    delta   = perm + BN;
  int*    pivi    = delta + BB*RES;
  unsigned char* ord8 = (unsigned char*)(pivi + BB*MAXP);

  float* out_pooled  = (float*)d_out;                   // B*MAXP*C
  float* out_shifted = out_pooled + BB*MAXP*CC;         // B*RES*FS
  float* out_piv     = out_shifted + (size_t)BB*RES*FS; // B*MAXP (as float)

  k_scores<<<(BN+255)/256, 256, 0, stream>>>(x, w, bsc, att, scoresd, s1d, s2d);
  k_sort  <<<BB, NN, 0, stream>>>(scoresd, perm);
  k_passA <<<dim3(NCH, BB), CHW, 0, stream>>>(x, perm, s1d, s2d, gkd, ord8, partial);
  k_gumbel<<<(BB*RES*16)/256, 256, 0, stream>>>(gkd, ord8, partial, epch, out_shifted, delta);
  k_chain <<<BB, 256, 0, stream>>>(delta, out_piv, pivi);
  k_pool  <<<(BB*MAXP*(CC/4)+255)/256, 256, 0, stream>>>(x, perm, pivi, out_pooled);
}

// Round 5
// 68.756 us; speedup vs baseline: 5.7179x; 1.2344x over previous
//
#include <hip/hip_runtime.h>
#include <math.h>

// Problem constants (from setup_inputs: B=128, N=512, C=64)
#define BB 128
#define NN 512
#define CC 64
#define FS 16
#define RES 497          // N - FS + 1
#define MAXP 256         // ceil(N * 0.5)
#define BN (BB*NN)       // 65536
#define GT (BB*RES*FS)   // 1017856
#define WPB 16           // windows per block (passA)
#define NCH 32           // ceil(RES/WPB)
#define ROWS (WPB+FS-1)  // 31 rows staged per block
#define PITCH 66         // float pitch: 8B-aligned rows, bank stride 2 -> worst 2-way (free)

// ---------------- Threefry-2x32 (JAX key (0,777), partitionable) ----------------
__device__ __forceinline__ unsigned rotl32(unsigned x, int d){ return (x<<d)|(x>>(32-d)); }

__device__ __forceinline__ void threefry777(unsigned x0, unsigned x1, unsigned &o0, unsigned &o1){
  const unsigned ks0 = 0u, ks1 = 777u;
  const unsigned ks2 = 0x1BD11BDAu ^ ks0 ^ ks1;
  x0 += ks0; x1 += ks1;
  x0+=x1; x1=rotl32(x1,13); x1^=x0;
  x0+=x1; x1=rotl32(x1,15); x1^=x0;
  x0+=x1; x1=rotl32(x1,26); x1^=x0;
  x0+=x1; x1=rotl32(x1, 6); x1^=x0;
  x0+=ks1; x1+=ks2+1u;
  x0+=x1; x1=rotl32(x1,17); x1^=x0;
  x0+=x1; x1=rotl32(x1,29); x1^=x0;
  x0+=x1; x1=rotl32(x1,16); x1^=x0;
  x0+=x1; x1=rotl32(x1,24); x1^=x0;
  x0+=ks2; x1+=ks0+2u;
  x0+=x1; x1=rotl32(x1,13); x1^=x0;
  x0+=x1; x1=rotl32(x1,15); x1^=x0;
  x0+=x1; x1=rotl32(x1,26); x1^=x0;
  x0+=x1; x1=rotl32(x1, 6); x1^=x0;
  x0+=ks0; x1+=ks1+3u;
  x0+=x1; x1=rotl32(x1,17); x1^=x0;
  x0+=x1; x1=rotl32(x1,29); x1^=x0;
  x0+=x1; x1=rotl32(x1,16); x1^=x0;
  x0+=x1; x1=rotl32(x1,24); x1^=x0;
  x0+=ks1; x1+=ks2+4u;
  x0+=x1; x1=rotl32(x1,13); x1^=x0;
  x0+=x1; x1=rotl32(x1,15); x1^=x0;
  x0+=x1; x1=rotl32(x1,26); x1^=x0;
  x0+=x1; x1=rotl32(x1, 6); x1^=x0;
  x0+=ks2; x1+=ks0+5u;
  o0 = x0; o1 = x1;
}

// Gumbel element p of flat (B,RES,FS): partitionable counter (0,p), bits=o0^o1,
// f32 uniform->gumbel (reference dtype), promoted to f64 at use site.
__device__ __forceinline__ float gumbel_at_f32(unsigned p){
  unsigned o0, o1;
  threefry777(0u, p, o0, o1);
  unsigned bits = o0 ^ o1;
  float fl = __uint_as_float((bits >> 9) | 0x3f800000u) - 1.0f;  // [0,1)
  float u  = fmaxf(1.17549435e-38f, fl);
  return -logf(-logf(u));
}

// push v to lane dstLane (0..63) within wave (ds_permute, all lanes must be active)
__device__ __forceinline__ double wave_push_f64(double v, int dstLane){
  int lo = __double2loint(v), hi = __double2hiint(v);
  int plo = __builtin_amdgcn_ds_permute(dstLane<<2, lo);
  int phi = __builtin_amdgcn_ds_permute(dstLane<<2, hi);
  return __hiloint2double(phi, plo);
}

// ---------------- K1: fused scores + stable descending bitonic argsort per graph ----------------
__global__ __launch_bounds__(NN) void k_scoresort(const float* __restrict__ x,
    const float* __restrict__ w, const float* __restrict__ bsc,
    const float* __restrict__ att, double* __restrict__ s1s,
    double* __restrict__ s2s, int* __restrict__ perm){
  int b = blockIdx.x, t = threadIdx.x;
  __shared__ double ss[NN];
  __shared__ int    si[NN];
  __shared__ double l1[NN], l2[NN];

  double wn=0.0, dw=0.0, d1=0.0, d2=0.0;
  #pragma unroll
  for (int c=0;c<CC;c++){ double wv=(double)w[c]; wn += wv*wv; }
  const float4* xr = (const float4*)(x + (size_t)(b*NN+t)*CC);
  #pragma unroll
  for (int q=0;q<CC/4;q++){
    float4 v = xr[q];
    double xv;
    xv=(double)v.x; dw+=xv*(double)w[4*q+0]; d1+=xv*(double)att[4*q+0]; d2+=xv*(double)att[CC+4*q+0];
    xv=(double)v.y; dw+=xv*(double)w[4*q+1]; d1+=xv*(double)att[4*q+1]; d2+=xv*(double)att[CC+4*q+1];
    xv=(double)v.z; dw+=xv*(double)w[4*q+2]; d1+=xv*(double)att[4*q+2]; d2+=xv*(double)att[CC+4*q+2];
    xv=(double)v.w; dw+=xv*(double)w[4*q+3]; d1+=xv*(double)att[4*q+3]; d2+=xv*(double)att[CC+4*q+3];
  }
  ss[t] = (dw + (double)bsc[0]) / sqrt(wn);
  si[t] = t;
  l1[t] = d1;
  l2[t] = d2;
  __syncthreads();

  for (int k = 2; k <= NN; k <<= 1){
    for (int j = k >> 1; j > 0; j >>= 1){
      int ixj = t ^ j;
      if (ixj > t){
        double s0 = ss[t], s1v = ss[ixj];
        int    i0 = si[t], i1  = si[ixj];
        bool before = (s0 > s1v) || (s0 == s1v && i0 < i1);   // (score desc, idx asc)
        bool up = ((t & k) == 0);
        if (up ? !before : before){
          ss[t] = s1v; ss[ixj] = s0;
          si[t] = i1;  si[ixj] = i0;
        }
      }
      __syncthreads();
    }
  }
  int orig = si[t];
  perm[b*NN + t] = orig;
  s1s[b*NN + t] = l1[orig];   // sorted-order a1 dot
  s2s[b*NN + t] = l2[orig];   // sorted-order a2 dot
}

// ---------------- K2: passA, 16 lanes = 1 window: gk, rank, colsum partial ----------------
__global__ __launch_bounds__(256) void k_passA(const float* __restrict__ x,
    const int* __restrict__ perm, const double* __restrict__ s1s,
    const double* __restrict__ s2s, double* __restrict__ gkd,
    unsigned char* __restrict__ rank8, double* __restrict__ partial){
  int b = blockIdx.y, ch = blockIdx.x, tid = threadIdx.x;
  int i0 = ch*WPB;
  int nwin  = min(WPB, RES - i0);
  int nrows = min(ROWS, NN - i0);
  __shared__ float  xs[ROWS*PITCH];   // ~8.2 KB
  __shared__ int    pg[ROWS];
  __shared__ double wred[4][FS];

  if (tid < nrows) pg[tid] = perm[b*NN + i0 + tid];
  __syncthreads();
  for (int u = tid; u < nrows*16; u += 256){
    int r = u >> 4, seg = u & 15;
    float4 v = ((const float4*)(x + (size_t)(b*NN + pg[r])*CC))[seg];
    float2* dst = (float2*)&xs[r*PITCH + seg*4];
    dst[0] = make_float2(v.x, v.y);
    dst[1] = make_float2(v.z, v.w);
  }
  __syncthreads();

  int w = tid >> 4, j = tid & 15;
  int lane = tid & 63, gbase = lane & 48, wv = tid >> 6;
  bool act = (w < nwin);
  int i = i0 + w;

  // squared distance (f64, sequential c order like the reference)
  double sq = 0.0;
  const float* rs = &xs[w*PITCH];
  const float* rd = &xs[(w+j)*PITCH];
  #pragma unroll
  for (int c2=0;c2<CC/2;c2++){
    float2 a  = *(const float2*)&rs[2*c2];
    float2 bb = *(const float2*)&rd[2*c2];
    double d0 = (double)a.x - (double)bb.x;
    double d1v= (double)a.y - (double)bb.y;
    sq += d0*d0;
    sq += d1v*d1v;
  }
  double d   = (sq > 0.0) ? sqrt(sq) : 0.0;     // safe_norm
  double gkv = exp(-d*0.5) - 1e-20;

  // window softmax term (f64, max-subtracted)
  int drow = min(i + j, NN-1);                   // clamp only hits inactive lanes
  double smt = s1s[b*NN + i] + s2s[b*NN + drow];
  double m = smt;
  #pragma unroll
  for (int off=8; off; off>>=1) m = fmax(m, __shfl_xor(m, off, 16));
  double em = exp(smt - m);
  double ssum = em;
  #pragma unroll
  for (int off=8; off; off>>=1) ssum += __shfl_xor(ssum, off, 16);
  double smn = em / ssum;

  // rank within window: #(k before j) under (gk desc, idx asc)
  int rank = 0;
  #pragma unroll
  for (int k=0;k<16;k++){
    double gkk = __shfl(gkv, gbase + k, 64);
    rank += ((gkk > gkv) || (gkk == gkv && k < j)) ? 1 : 0;
  }

  if (act){
    size_t base = ((size_t)b*RES + i)*FS;
    gkd[base + j]   = gkv;
    rank8[base + j] = (unsigned char)rank;
  }

  // scatter softmax term to its rank lane, then sum windows (deterministic order)
  double contrib = act ? smn : 0.0;
  double srt = wave_push_f64(contrib, gbase + rank);
  srt += __shfl_xor(srt, 16, 64);
  srt += __shfl_xor(srt, 32, 64);
  if (lane < FS) wred[wv][lane] = srt;
  __syncthreads();
  if (tid < FS){
    partial[((size_t)b*NCH + ch)*FS + tid] =
        wred[0][tid] + wred[1][tid] + wred[2][tid] + wred[3][tid];
  }
}

// ---------------- K3: reduce colsum partials (deterministic sequential order) ----------------
__global__ void k_colsum(const double* __restrict__ partial, double* __restrict__ colsum){
  int t = blockIdx.x*blockDim.x + threadIdx.x;
  if (t >= BB*FS) return;
  int b = t >> 4, s = t & 15;
  double acc = 0.0;
  #pragma unroll
  for (int ch=0; ch<NCH; ch++) acc += partial[((size_t)b*NCH + ch)*FS + s];
  colsum[t] = acc;
}

// ---------------- K4: 16 lanes per window: gumbel-softmax, ths, shifted, delta ----------------
__global__ void k_gumbel(const double* __restrict__ gkd, const unsigned char* __restrict__ rank8,
                         const double* __restrict__ colsum, const int* __restrict__ epoch_p,
                         float* __restrict__ shifted_out, int* __restrict__ delta){
  int t = blockIdx.x*blockDim.x + threadIdx.x;
  int win = t >> 4, s = t & 15;
  if (win >= BB*RES) return;
  int lane = threadIdx.x & 63, gbase = lane & 48;
  int b = win / RES;
  size_t base = (size_t)win * FS;
  double tau = 10.0 * pow(0.01, (double)epoch_p[0] / 100.0);

  double z;
  if (s == 0) z = -(double)INFINITY;
  else {
    double g = (double)gumbel_at_f32((unsigned)(base + (unsigned)s));
    z = (g + colsum[b*FS + s]) / tau;
  }
  double m = z;
  #pragma unroll
  for (int off=8; off; off>>=1) m = fmax(m, __shfl_xor(m, off, 16));
  double e = (s == 0) ? 0.0 : exp(z - m);
  double ssum = e;
  #pragma unroll
  for (int off=8; off; off>>=1) ssum += __shfl_xor(ssum, off, 16);
  double gmb = e / ssum;

  double gkv = gkd[base + s];
  int rk = rank8[base + s];
  double gmbr = __shfl(gmb, gbase + rk, 64);   // gmb at my rank position
  double ths = gkv * gmbr;
  #pragma unroll
  for (int off=8; off; off>>=1) ths += __shfl_xor(ths, off, 16);

  double shv = fmax(gkv - ths, 0.0);
  shifted_out[base + s] = (float)shv;

  double av = (s == 0) ? (double)INFINITY : shv;   // argmin over j=1..15, first-min wins
  int ai = s;
  #pragma unroll
  for (int off=8; off; off>>=1){
    double ov = __shfl_xor(av, off, 16);
    int    oi = __shfl_xor(ai, off, 16);
    if (ov < av || (ov == av && oi < ai)){ av = ov; ai = oi; }
  }
  if (s == 0) delta[win] = ai;
}

// ---------------- K5: pivot chain via pointer-doubling jump tables ----------------
__global__ __launch_bounds__(256) void k_chain(const int* __restrict__ delta,
                                               float* __restrict__ piv_out,
                                               int* __restrict__ pivi){
  int b = blockIdx.x, tid = threadIdx.x;
  __shared__ int tbl[8][512];
  for (int i = tid; i < 512; i += 256){
    int v;
    if (i < RES){ v = i + delta[b*RES + i]; if (v > RES) v = RES; }
    else v = RES;                 // absorbing sentinel
    tbl[0][i] = v;
  }
  __syncthreads();
  #pragma unroll
  for (int k=1;k<8;k++){
    int v0 = tbl[k-1][tid];
    int v1 = tbl[k-1][tid+256];
    tbl[k][tid]     = tbl[k-1][v0];
    tbl[k][tid+256] = tbl[k-1][v1];
    __syncthreads();
  }
  int p = 0;
  #pragma unroll
  for (int k=0;k<8;k++) if ((tid>>k)&1) p = tbl[k][p];
  int piv = (p < RES) ? p : -1;
  piv_out[b*MAXP + tid] = (float)piv;
  pivi[b*MAXP + tid]    = piv;
}

// ---------------- K6: pooled gather (masked) ----------------
__global__ void k_pool(const float* __restrict__ x, const int* __restrict__ perm,
                       const int* __restrict__ pivi, float* __restrict__ pooled){
  int t = blockIdx.x*blockDim.x + threadIdx.x;
  const int total = BB*MAXP*(CC/4);
  if (t >= total) return;
  int c4 = t & 15;
  int bp = t >> 4;
  int piv = pivi[bp];
  float4 v = make_float4(0.f,0.f,0.f,0.f);
  if (piv >= 0){
    int b = bp / MAXP;
    int src = perm[b*NN + piv];
    v = ((const float4*)(x + (size_t)(b*NN + src)*CC))[c4];
  }
  ((float4*)pooled)[t] = v;
}

extern "C" void kernel_launch(void* const* d_in, const int* in_sizes, int n_in,
                              void* d_out, int out_size, void* d_ws, size_t ws_size,
                              hipStream_t stream) {
  (void)in_sizes; (void)n_in; (void)out_size; (void)ws_size;
  const float* x    = (const float*)d_in[0];
  const float* w    = (const float*)d_in[1];
  const float* bsc  = (const float*)d_in[2];
  const float* att  = (const float*)d_in[3];
  const int*   epch = (const int*)d_in[5];

  // workspace layout (~10.9 MiB), f64 first for alignment
  double* s1s     = (double*)d_ws;            // BN
  double* s2s     = s1s + BN;                 // BN
  double* gkd     = s2s + BN;                 // GT
  double* partial = gkd + GT;                 // BB*NCH*FS
  double* colsumd = partial + (size_t)BB*NCH*FS; // BB*FS
  int*    perm    = (int*)(colsumd + BB*FS);  // BN
  int*    delta   = perm + BN;                // BB*RES
  int*    pivi    = delta + BB*RES;           // BB*MAXP
  unsigned char* rank8 = (unsigned char*)(pivi + BB*MAXP); // GT bytes

  float* out_pooled  = (float*)d_out;                   // B*MAXP*C
  float* out_shifted = out_pooled + BB*MAXP*CC;         // B*RES*FS
  float* out_piv     = out_shifted + (size_t)BB*RES*FS; // B*MAXP (as float)

  k_scoresort<<<BB, NN, 0, stream>>>(x, w, bsc, att, s1s, s2s, perm);
  k_passA <<<dim3(NCH, BB), 256, 0, stream>>>(x, perm, s1s, s2s, gkd, rank8, partial);
  k_colsum<<<(BB*FS+255)/256, 256, 0, stream>>>(partial, colsumd);
  k_gumbel<<<(BB*RES*16+255)/256, 256, 0, stream>>>(gkd, rank8, colsumd, epch, out_shifted, delta);
  k_chain <<<BB, 256, 0, stream>>>(delta, out_piv, pivi);
  k_pool  <<<(BB*MAXP*(CC/4)+255)/256, 256, 0, stream>>>(x, perm, pivi, out_pooled);
}

// Round 6
// 66.395 us; speedup vs baseline: 5.9213x; 1.0356x over previous
//
#include <hip/hip_runtime.h>
#include <math.h>

// Problem constants (from setup_inputs: B=128, N=512, C=64)
#define BB 128
#define NN 512
#define CC 64
#define FS 16
#define RES 497          // N - FS + 1
#define MAXP 256         // ceil(N * 0.5)
#define BN (BB*NN)       // 65536
#define GT (BB*RES*FS)   // 1017856
#define WPB 16           // windows per block (passA)
#define NCH 32           // ceil(RES/WPB)
#define ROWS (WPB+FS-1)  // 31 rows staged per block
#define PITCH 66         // float pitch: 8B-aligned rows, bank stride 2 -> worst 2-way (free)

// ---------------- Threefry-2x32 (JAX key (0,777), partitionable) ----------------
__device__ __forceinline__ unsigned rotl32(unsigned x, int d){ return (x<<d)|(x>>(32-d)); }

__device__ __forceinline__ void threefry777(unsigned x0, unsigned x1, unsigned &o0, unsigned &o1){
  const unsigned ks0 = 0u, ks1 = 777u;
  const unsigned ks2 = 0x1BD11BDAu ^ ks0 ^ ks1;
  x0 += ks0; x1 += ks1;
  x0+=x1; x1=rotl32(x1,13); x1^=x0;
  x0+=x1; x1=rotl32(x1,15); x1^=x0;
  x0+=x1; x1=rotl32(x1,26); x1^=x0;
  x0+=x1; x1=rotl32(x1, 6); x1^=x0;
  x0+=ks1; x1+=ks2+1u;
  x0+=x1; x1=rotl32(x1,17); x1^=x0;
  x0+=x1; x1=rotl32(x1,29); x1^=x0;
  x0+=x1; x1=rotl32(x1,16); x1^=x0;
  x0+=x1; x1=rotl32(x1,24); x1^=x0;
  x0+=ks2; x1+=ks0+2u;
  x0+=x1; x1=rotl32(x1,13); x1^=x0;
  x0+=x1; x1=rotl32(x1,15); x1^=x0;
  x0+=x1; x1=rotl32(x1,26); x1^=x0;
  x0+=x1; x1=rotl32(x1, 6); x1^=x0;
  x0+=ks0; x1+=ks1+3u;
  x0+=x1; x1=rotl32(x1,17); x1^=x0;
  x0+=x1; x1=rotl32(x1,29); x1^=x0;
  x0+=x1; x1=rotl32(x1,16); x1^=x0;
  x0+=x1; x1=rotl32(x1,24); x1^=x0;
  x0+=ks1; x1+=ks2+4u;
  x0+=x1; x1=rotl32(x1,13); x1^=x0;
  x0+=x1; x1=rotl32(x1,15); x1^=x0;
  x0+=x1; x1=rotl32(x1,26); x1^=x0;
  x0+=x1; x1=rotl32(x1, 6); x1^=x0;
  x0+=ks2; x1+=ks0+5u;
  o0 = x0; o1 = x1;
}

// Gumbel element p of flat (B,RES,FS): partitionable counter (0,p), bits=o0^o1,
// f32 uniform->gumbel (reference dtype), promoted to f64 at use site.
__device__ __forceinline__ float gumbel_at_f32(unsigned p){
  unsigned o0, o1;
  threefry777(0u, p, o0, o1);
  unsigned bits = o0 ^ o1;
  float fl = __uint_as_float((bits >> 9) | 0x3f800000u) - 1.0f;  // [0,1)
  float u  = fmaxf(1.17549435e-38f, fl);
  return -logf(-logf(u));
}

// push v to lane dstLane (0..63) within wave (ds_permute, all lanes must be active)
__device__ __forceinline__ double wave_push_f64(double v, int dstLane){
  int lo = __double2loint(v), hi = __double2hiint(v);
  int plo = __builtin_amdgcn_ds_permute(dstLane<<2, lo);
  int phi = __builtin_amdgcn_ds_permute(dstLane<<2, hi);
  return __hiloint2double(phi, plo);
}

// ---------------- K1: fused scores + stable descending bitonic argsort per graph ----------
// j<=32 stages: in-wave register shfl_xor compare-exchange (no LDS, no sync).
// j>=64 stages (6 of them): LDS exchange. Comparator identical to previous rounds.
__global__ __launch_bounds__(NN) void k_scoresort(const float* __restrict__ x,
    const float* __restrict__ w, const float* __restrict__ bsc,
    const float* __restrict__ att, double* __restrict__ s1s,
    double* __restrict__ s2s, int* __restrict__ perm){
  int b = blockIdx.x, t = threadIdx.x;
  __shared__ double ss[NN];
  __shared__ int    si[NN];
  __shared__ double l1[NN], l2[NN];

  double wn=0.0, dw=0.0, d1=0.0, d2=0.0;
  #pragma unroll
  for (int c=0;c<CC;c++){ double wv=(double)w[c]; wn += wv*wv; }
  const float4* xr = (const float4*)(x + (size_t)(b*NN+t)*CC);
  #pragma unroll
  for (int q=0;q<CC/4;q++){
    float4 v = xr[q];
    double xv;
    xv=(double)v.x; dw+=xv*(double)w[4*q+0]; d1+=xv*(double)att[4*q+0]; d2+=xv*(double)att[CC+4*q+0];
    xv=(double)v.y; dw+=xv*(double)w[4*q+1]; d1+=xv*(double)att[4*q+1]; d2+=xv*(double)att[CC+4*q+1];
    xv=(double)v.z; dw+=xv*(double)w[4*q+2]; d1+=xv*(double)att[4*q+2]; d2+=xv*(double)att[CC+4*q+2];
    xv=(double)v.w; dw+=xv*(double)w[4*q+3]; d1+=xv*(double)att[4*q+3]; d2+=xv*(double)att[CC+4*q+3];
  }
  double s = (dw + (double)bsc[0]) / sqrt(wn);
  int idx = t;
  l1[t] = d1;
  l2[t] = d2;

  // before(a,b) = (a.s > b.s) || (a.s == b.s && a.i < b.i)  — total order (idx unique)
  for (int k = 2; k <= NN; k <<= 1){
    bool up = ((t & k) == 0);
    // cross-wave stages via LDS
    for (int j = k >> 1; j >= 64; j >>= 1){
      ss[t] = s; si[t] = idx;
      __syncthreads();
      double os = ss[t ^ j]; int oi = si[t ^ j];
      bool first = ((t & j) == 0);
      bool cmp = (s > os) || (s == os && idx < oi);
      bool keep = (cmp == (first == up));
      if (!keep){ s = os; idx = oi; }
      __syncthreads();
    }
    // in-wave stages via register shuffles
    #pragma unroll
    for (int j = 32; j > 0; j >>= 1){
      if (j <= (k >> 1)){
        double os = __shfl_xor(s, j, 64);
        int    oi = __shfl_xor(idx, j, 64);
        bool first = ((t & j) == 0);
        bool cmp = (s > os) || (s == os && idx < oi);
        bool keep = (cmp == (first == up));
        if (!keep){ s = os; idx = oi; }
      }
    }
  }
  __syncthreads();          // l1/l2 writes visible (they were before the sort loop)
  perm[b*NN + t] = idx;
  s1s[b*NN + t] = l1[idx];  // sorted-order a1 dot
  s2s[b*NN + t] = l2[idx];  // sorted-order a2 dot
}

// ---------------- K2: passA, 16 lanes = 1 window: gk, rank, colsum partial ----------------
__global__ __launch_bounds__(256) void k_passA(const float* __restrict__ x,
    const int* __restrict__ perm, const double* __restrict__ s1s,
    const double* __restrict__ s2s, double* __restrict__ gkd,
    unsigned char* __restrict__ rank8, double* __restrict__ partial){
  int b = blockIdx.y, ch = blockIdx.x, tid = threadIdx.x;
  int i0 = ch*WPB;
  int nwin  = min(WPB, RES - i0);
  int nrows = min(ROWS, NN - i0);
  __shared__ float  xs[ROWS*PITCH];   // ~8.2 KB
  __shared__ int    pg[ROWS];
  __shared__ double wred[4][FS];

  if (tid < nrows) pg[tid] = perm[b*NN + i0 + tid];
  __syncthreads();
  for (int u = tid; u < nrows*16; u += 256){
    int r = u >> 4, seg = u & 15;
    float4 v = ((const float4*)(x + (size_t)(b*NN + pg[r])*CC))[seg];
    float2* dst = (float2*)&xs[r*PITCH + seg*4];
    dst[0] = make_float2(v.x, v.y);
    dst[1] = make_float2(v.z, v.w);
  }
  __syncthreads();

  int w = tid >> 4, j = tid & 15;
  int lane = tid & 63, gbase = lane & 48, wv = tid >> 6;
  bool act = (w < nwin);
  int i = i0 + w;

  // squared distance (f64, sequential c order like the reference)
  double sq = 0.0;
  const float* rs = &xs[w*PITCH];
  const float* rd = &xs[(w+j)*PITCH];
  #pragma unroll
  for (int c2=0;c2<CC/2;c2++){
    float2 a  = *(const float2*)&rs[2*c2];
    float2 bb = *(const float2*)&rd[2*c2];
    double d0 = (double)a.x - (double)bb.x;
    double d1v= (double)a.y - (double)bb.y;
    sq += d0*d0;
    sq += d1v*d1v;
  }
  double d   = (sq > 0.0) ? sqrt(sq) : 0.0;     // safe_norm
  double gkv = exp(-d*0.5) - 1e-20;

  // window softmax term (f64, max-subtracted)
  int drow = min(i + j, NN-1);                   // clamp only hits inactive lanes
  double smt = s1s[b*NN + i] + s2s[b*NN + drow];
  double m = smt;
  #pragma unroll
  for (int off=8; off; off>>=1) m = fmax(m, __shfl_xor(m, off, 16));
  double em = exp(smt - m);
  double ssum = em;
  #pragma unroll
  for (int off=8; off; off>>=1) ssum += __shfl_xor(ssum, off, 16);
  double smn = em / ssum;

  // rank within window: #(k before j) under (gk desc, idx asc)
  int rank = 0;
  #pragma unroll
  for (int k=0;k<16;k++){
    double gkk = __shfl(gkv, gbase + k, 64);
    rank += ((gkk > gkv) || (gkk == gkv && k < j)) ? 1 : 0;
  }

  if (act){
    size_t base = ((size_t)b*RES + i)*FS;
    gkd[base + j]   = gkv;
    rank8[base + j] = (unsigned char)rank;
  }

  // scatter softmax term to its rank lane, then sum windows (deterministic order)
  double contrib = act ? smn : 0.0;
  double srt = wave_push_f64(contrib, gbase + rank);
  srt += __shfl_xor(srt, 16, 64);
  srt += __shfl_xor(srt, 32, 64);
  if (lane < FS) wred[wv][lane] = srt;
  __syncthreads();
  if (tid < FS){
    partial[((size_t)b*NCH + ch)*FS + tid] =
        wred[0][tid] + wred[1][tid] + wred[2][tid] + wred[3][tid];
  }
}

// ---------------- K3: fused per-graph tail: colsum + gumbel-softmax + ths/shifted/delta
//                     + pivot chain (pointer doubling) + pooled gather ----------------
__global__ __launch_bounds__(1024) void k_tail(const double* __restrict__ gkd,
    const unsigned char* __restrict__ rank8, const double* __restrict__ partial,
    const int* __restrict__ epoch_p, const int* __restrict__ perm,
    const float* __restrict__ x, float* __restrict__ shifted_out,
    float* __restrict__ piv_out, float* __restrict__ pooled){
  int b = blockIdx.x, tid = threadIdx.x;
  __shared__ double pl[NCH*FS];     // 4 KB
  __shared__ double cs[FS];
  __shared__ int    tbl[8][512];    // 16 KB
  __shared__ int    pivS[MAXP];

  // colsum: load all partials, reduce in the same sequential ch order as before
  if (tid < NCH*FS) pl[tid] = partial[(size_t)b*NCH*FS + tid];
  for (int i2 = tid; i2 < 512; i2 += 1024) if (i2 >= RES) tbl[0][i2] = RES;  // absorbing
  __syncthreads();
  if (tid < FS){
    double a = 0.0;
    #pragma unroll
    for (int ch=0; ch<NCH; ch++) a += pl[ch*FS + tid];
    cs[tid] = a;
  }
  __syncthreads();

  double tau = 10.0 * pow(0.01, (double)epoch_p[0] / 100.0);
  int lane = tid & 63, gbase = lane & 48;
  int s = tid & 15;

  #pragma unroll
  for (int it=0; it<8; it++){
    int win = it*64 + (tid >> 4);      // 1024 threads = 64 windows per iteration
    if (win < RES){
      size_t base = ((size_t)b*RES + win)*FS;
      double z;
      if (s == 0) z = -(double)INFINITY;
      else {
        double g = (double)gumbel_at_f32((unsigned)(base + (unsigned)s));
        z = (g + cs[s]) / tau;
      }
      double m = z;
      #pragma unroll
      for (int off=8; off; off>>=1) m = fmax(m, __shfl_xor(m, off, 16));
      double e = (s == 0) ? 0.0 : exp(z - m);
      double ssum = e;
      #pragma unroll
      for (int off=8; off; off>>=1) ssum += __shfl_xor(ssum, off, 16);
      double gmb = e / ssum;

      double gkv = gkd[base + s];
      int rk = rank8[base + s];
      double gmbr = __shfl(gmb, gbase + rk, 64);   // gmb at my rank position
      double ths = gkv * gmbr;
      #pragma unroll
      for (int off=8; off; off>>=1) ths += __shfl_xor(ths, off, 16);

      double shv = fmax(gkv - ths, 0.0);
      shifted_out[base + s] = (float)shv;

      double av = (s == 0) ? (double)INFINITY : shv;   // argmin over j=1..15, first-min wins
      int ai = s;
      #pragma unroll
      for (int off=8; off; off>>=1){
        double ov = __shfl_xor(av, off, 16);
        int    oi = __shfl_xor(ai, off, 16);
        if (ov < av || (ov == av && oi < ai)){ av = ov; ai = oi; }
      }
      if (s == 0){
        int v = win + ai;                 // delta = ai
        tbl[0][win] = (v > RES) ? RES : v;
      }
    }
  }
  __syncthreads();

  // pointer doubling
  #pragma unroll
  for (int k=1;k<8;k++){
    if (tid < 512){ int v = tbl[k-1][tid]; tbl[k][tid] = tbl[k-1][v]; }
    __syncthreads();
  }
  if (tid < MAXP){
    int p = 0;
    #pragma unroll
    for (int k=0;k<8;k++) if ((tid>>k)&1) p = tbl[k][p];
    int piv = (p < RES) ? p : -1;
    pivS[tid] = piv;
    piv_out[b*MAXP + tid] = (float)piv;
  }
  __syncthreads();

  // pooled gather (masked)
  for (int u = tid; u < MAXP*16; u += 1024){
    int bp = u >> 4, seg = u & 15;
    int piv = pivS[bp];
    float4 v = make_float4(0.f,0.f,0.f,0.f);
    if (piv >= 0){
      int src = perm[b*NN + piv];
      v = ((const float4*)(x + (size_t)(b*NN + src)*CC))[seg];
    }
    ((float4*)pooled)[(size_t)(b*MAXP + bp)*16 + seg] = v;
  }
}

extern "C" void kernel_launch(void* const* d_in, const int* in_sizes, int n_in,
                              void* d_out, int out_size, void* d_ws, size_t ws_size,
                              hipStream_t stream) {
  (void)in_sizes; (void)n_in; (void)out_size; (void)ws_size;
  const float* x    = (const float*)d_in[0];
  const float* w    = (const float*)d_in[1];
  const float* bsc  = (const float*)d_in[2];
  const float* att  = (const float*)d_in[3];
  const int*   epch = (const int*)d_in[5];

  // workspace layout (~10.5 MiB), f64 first for alignment
  double* s1s     = (double*)d_ws;               // BN
  double* s2s     = s1s + BN;                    // BN
  double* gkd     = s2s + BN;                    // GT
  double* partial = gkd + GT;                    // BB*NCH*FS
  int*    perm    = (int*)(partial + (size_t)BB*NCH*FS); // BN
  unsigned char* rank8 = (unsigned char*)(perm + BN);    // GT bytes

  float* out_pooled  = (float*)d_out;                   // B*MAXP*C
  float* out_shifted = out_pooled + BB*MAXP*CC;         // B*RES*FS
  float* out_piv     = out_shifted + (size_t)BB*RES*FS; // B*MAXP (as float)

  k_scoresort<<<BB, NN, 0, stream>>>(x, w, bsc, att, s1s, s2s, perm);
  k_passA <<<dim3(NCH, BB), 256, 0, stream>>>(x, perm, s1s, s2s, gkd, rank8, partial);
  k_tail  <<<BB, 1024, 0, stream>>>(gkd, rank8, partial, epch, perm, x,
                                    out_shifted, out_piv, out_pooled);
}